// Round 3
// baseline (481.168 us; speedup 1.0000x reference)
//
#include <hip/hip_runtime.h>
#include <cstdint>
#include <cstddef>

typedef unsigned short u16;
typedef __attribute__((ext_vector_type(4))) float floatx4;
typedef __attribute__((ext_vector_type(8))) __bf16 bf16x8;

// ---------- bf16 helpers (bf16 buffers held as u16) ----------
__device__ __forceinline__ float u2f(u16 u) {
    union { unsigned int i; float f; } x;
    x.i = ((unsigned int)u) << 16;
    return x.f;
}
__device__ __forceinline__ u16 f2u(float f) {
    union { float f; unsigned int i; } x;
    x.f = f;
    unsigned int r = x.i + 0x7fffu + ((x.i >> 16) & 1u);   // RNE
    return (u16)(r >> 16);
}

// ---------- fused transpose + fp32->bf16: in (K x N) f32 -> out (N x K) bf16 ----------
__global__ __launch_bounds__(256) void transpose_f32_bf16(const float* __restrict__ in,
                                                          u16* __restrict__ out,
                                                          int K, int N) {
    __shared__ float tile[32][33];
    int n0 = blockIdx.x * 32, k0 = blockIdx.y * 32;
    int tx = threadIdx.x & 31, ty = threadIdx.x >> 5;   // ty 0..7
#pragma unroll
    for (int j = 0; j < 4; ++j) {
        int r = ty + j * 8;
        tile[r][tx] = in[(size_t)(k0 + r) * N + n0 + tx];
    }
    __syncthreads();
#pragma unroll
    for (int j = 0; j < 4; ++j) {
        int r = ty + j * 8;
        out[(size_t)(n0 + r) * K + k0 + tx] = f2u(tile[tx][r]);
    }
}

// ---------- layernorm over D=1024 (f32 in), rows = 4096, bf16 out ----------
__global__ __launch_bounds__(256) void ln_kernel(const float* __restrict__ x,
                                                 const float* __restrict__ gamma,
                                                 const float* __restrict__ beta,
                                                 u16* __restrict__ h) {
    int r = blockIdx.x, t = threadIdx.x;
    const float4* xr = (const float4*)(x + (size_t)r * 1024);
    float4 xv = xr[t];
    float s = xv.x + xv.y + xv.z + xv.w;
    float ss = xv.x * xv.x + xv.y * xv.y + xv.z * xv.z + xv.w * xv.w;
#pragma unroll
    for (int off = 32; off > 0; off >>= 1) {
        s += __shfl_down(s, off, 64);
        ss += __shfl_down(ss, off, 64);
    }
    __shared__ float rs[4], rss[4];
    __shared__ float mu_s, ri_s;
    int wave = t >> 6, lane = t & 63;
    if (lane == 0) { rs[wave] = s; rss[wave] = ss; }
    __syncthreads();
    if (t == 0) {
        float S = rs[0] + rs[1] + rs[2] + rs[3];
        float SS = rss[0] + rss[1] + rss[2] + rss[3];
        float mu = S * (1.f / 1024.f);
        float var = SS * (1.f / 1024.f) - mu * mu;
        mu_s = mu;
        ri_s = rsqrtf(fmaxf(var, 0.f) + 1e-5f);
    }
    __syncthreads();
    float mu = mu_s, ri = ri_s;
    const float4* gv4 = (const float4*)gamma;
    const float4* bv4 = (const float4*)beta;
    float4 gv = gv4[t], bv = bv4[t];
    ushort4 o;
    o.x = f2u((xv.x - mu) * ri * gv.x + bv.x);
    o.y = f2u((xv.y - mu) * ri * gv.y + bv.y);
    o.z = f2u((xv.z - mu) * ri * gv.z + bv.z);
    o.w = f2u((xv.w - mu) * ri * gv.w + bv.w);
    ((ushort4*)(h + (size_t)r * 1024))[t] = o;
}

// ---------- MFMA GEMM: A (MxK) bf16 * Bt^T (Bt is NxK bf16), 128x128 tile ----------
__device__ __forceinline__ void gl_lds16(const u16* g, u16* l) {
    __builtin_amdgcn_global_load_lds(
        (const __attribute__((address_space(1))) void*)g,
        (__attribute__((address_space(3))) void*)l, 16, 0, 0);
}

// EPI: 0 = store bf16
//      1 = delta fusion: atomicAdd per-row sum of softplus(acc + biasf32[col]) into (float*)out
//      2 = fp32 store of (acc + residf32[idx])
template <int EPI>
__global__ __launch_bounds__(256)
void gemm128(const u16* __restrict__ A, const u16* __restrict__ Bt,
             void* __restrict__ out, const void* __restrict__ aux,
             int M, int N, int K) {
    __shared__ u16 As[128 * 32];
    __shared__ u16 Bs[128 * 32];
    const int tid = threadIdx.x;
    const int wave = tid >> 6, lane = tid & 63;
    const int row0 = blockIdx.y * 128, col0 = blockIdx.x * 128;
    const int l16 = lane & 15, q = lane >> 4;
    const int wr = wave >> 1, wc = wave & 1;

    floatx4 acc[4][4];
#pragma unroll
    for (int i = 0; i < 4; ++i)
#pragma unroll
        for (int j = 0; j < 4; ++j) acc[i][j] = (floatx4){0.f, 0.f, 0.f, 0.f};

    const int sRow = lane >> 2;          // 0..15
    const int sK = (lane & 3) * 8;       // 0,8,16,24
    const u16* gA = A + (size_t)(row0 + wave * 32 + sRow) * K + sK;
    const u16* gB = Bt + (size_t)(col0 + wave * 32 + sRow) * K + sK;
    u16* lA = As + wave * 1024;          // wave-uniform LDS base
    u16* lB = Bs + wave * 1024;

    for (int k0 = 0; k0 < K; k0 += 32) {
        gl_lds16(gA, lA);
        gl_lds16(gA + (size_t)16 * K, lA + 512);
        gl_lds16(gB, lB);
        gl_lds16(gB + (size_t)16 * K, lB + 512);
        gA += 32; gB += 32;
        __syncthreads();   // vmcnt(0) drain + barrier: staging visible

        bf16x8 af[4], bfr[4];
#pragma unroll
        for (int i = 0; i < 4; ++i)
            af[i] = *(const bf16x8*)(As + ((wr * 64 + i * 16 + l16) * 32 + q * 8));
#pragma unroll
        for (int i = 0; i < 4; ++i)
            bfr[i] = *(const bf16x8*)(Bs + ((wc * 64 + i * 16 + l16) * 32 + q * 8));
#pragma unroll
        for (int mi = 0; mi < 4; ++mi)
#pragma unroll
            for (int ni = 0; ni < 4; ++ni)
                acc[mi][ni] = __builtin_amdgcn_mfma_f32_16x16x32_bf16(
                    af[mi], bfr[ni], acc[mi][ni], 0, 0, 0);
        __syncthreads();   // compute done before next-stage overwrite
    }

    // epilogue: D row = q*4 + reg, col = l16 (verified m89/m91 mapping)
    const int mB = row0 + wr * 64;
    const int nB = col0 + wc * 64 + l16;
    if constexpr (EPI == 1) {
        float* dacc = (float*)out;
        const float* bias = (const float*)aux;
#pragma unroll
        for (int mi = 0; mi < 4; ++mi) {
#pragma unroll
            for (int rr = 0; rr < 4; ++rr) {
                float s = 0.f;
#pragma unroll
                for (int ni = 0; ni < 4; ++ni) {
                    int col = nB + ni * 16;
                    float t2 = acc[mi][ni][rr] + bias[col];
                    s += (t2 > 20.f) ? t2 : log1pf(expf(t2));
                }
#pragma unroll
                for (int off = 1; off < 16; off <<= 1)
                    s += __shfl_xor(s, off, 64);
                if (l16 == 0) {
                    int row = mB + mi * 16 + q * 4 + rr;
                    atomicAdd(&dacc[row], s);
                }
            }
        }
    } else {
#pragma unroll
        for (int mi = 0; mi < 4; ++mi) {
#pragma unroll
            for (int ni = 0; ni < 4; ++ni) {
                int col = nB + ni * 16;
#pragma unroll
                for (int rr = 0; rr < 4; ++rr) {
                    int row = mB + mi * 16 + q * 4 + rr;
                    size_t idx = (size_t)row * N + col;
                    float v = acc[mi][ni][rr];
                    if constexpr (EPI == 0) {
                        ((u16*)out)[idx] = f2u(v);
                    } else {
                        ((float*)out)[idx] = v + ((const float*)aux)[idx];
                    }
                }
            }
        }
    }
}

// ---------- depthwise causal conv (K=4, f32 wts) + SiLU. xg rows: [xs(2048)|gate(2048)] bf16 ----------
__global__ __launch_bounds__(256) void conv_silu_kernel(const u16* __restrict__ xg,
                                                        const float* __restrict__ conv_w,
                                                        const float* __restrict__ conv_b,
                                                        u16* __restrict__ xsc) {
    int d = blockIdx.x * 256 + threadIdx.x;   // 0..2047
    int r = blockIdx.y;                       // 0..4095
    int l = r & 2047, bb = r >> 11;
    float acc = conv_b[d];
#pragma unroll
    for (int k = 0; k < 4; ++k) {
        int ls = l + k - 3;
        if (ls >= 0)
            acc += conv_w[d * 4 + k] * u2f(xg[(size_t)((bb << 11) + ls) * 4096 + d]);
    }
    float s = acc / (1.f + expf(-acc));
    xsc[(size_t)r * 2048 + d] = f2u(s);
}

// ---------- Bx[r][n] = delta*<xsc[r,:],B_mat[n,:]>, dA[r][n] = exp(delta*-exp(A_log[n])) ----------
__global__ __launch_bounds__(256) void bxda_kernel(const u16* __restrict__ xsc,
                                                   const float* __restrict__ B_mat,
                                                   const float* __restrict__ A_log,
                                                   const float* __restrict__ delta_acc,
                                                   float* __restrict__ dA,
                                                   float* __restrict__ Bx) {
    int r = blockIdx.x, t = threadIdx.x;
    int n = t & 15, c = t >> 4;
    const u16* xr = xsc + (size_t)r * 2048;
    const float* br = B_mat + (size_t)n * 2048;
    float acc = 0.f;
    int d0 = c * 128;
#pragma unroll 8
    for (int i = 0; i < 128; ++i) acc += u2f(xr[d0 + i]) * br[d0 + i];
    __shared__ float red[256];
    red[t] = acc;
    __syncthreads();
    for (int s = 128; s >= 16; s >>= 1) {
        if (t < s) red[t] += red[t + s];
        __syncthreads();
    }
    if (t < 16) {
        float dl = delta_acc[r] * (1.f / 2048.f);
        float An = -expf(A_log[t]);
        size_t idx = (size_t)r * 16 + t;
        dA[idx] = expf(dl * An);
        Bx[idx] = red[t] * dl;
    }
}

// ---------- parallel selective scan: 32 chains, 1 wave each, affine-composition scan ----------
__global__ __launch_bounds__(64) void scan_kernel(const float* __restrict__ dA,
                                                  const float* __restrict__ Bx,
                                                  float* __restrict__ hs) {
    int chain = blockIdx.x;                 // 0..31
    int b = chain >> 4, n = chain & 15;
    int j = threadIdx.x;                    // 0..63, chunk of 32 l's each
    size_t base = ((size_t)b * 2048 + (size_t)j * 32) * 16 + n;
    float a[32], bb[32];
#pragma unroll
    for (int i = 0; i < 32; ++i) {
        a[i] = dA[base + (size_t)i * 16];
        bb[i] = Bx[base + (size_t)i * 16];
    }
    float Aacc = 1.f, Bacc = 0.f;
#pragma unroll
    for (int i = 0; i < 32; ++i) {
        Bacc = a[i] * Bacc + bb[i];
        Aacc = a[i] * Aacc;
    }
#pragma unroll
    for (int d = 1; d < 64; d <<= 1) {
        float Ap = __shfl_up(Aacc, d, 64);
        float Bp = __shfl_up(Bacc, d, 64);
        if (j >= d) {
            Bacc = Aacc * Bp + Bacc;
            Aacc = Aacc * Ap;
        }
    }
    float hstart = __shfl_up(Bacc, 1, 64);
    if (j == 0) hstart = 0.f;
    float h = hstart;
#pragma unroll
    for (int i = 0; i < 32; ++i) {
        h = a[i] * h + bb[i];
        hs[base + (size_t)i * 16] = h;
    }
}

// ---------- ymid = (hs·C_mat[d,:] + D_vec*xsc) * silu(gate), bf16 out ----------
__global__ __launch_bounds__(256) void ymid_kernel(const float* __restrict__ hs,
                                                   const float* __restrict__ C_mat,
                                                   const float* __restrict__ D_vec,
                                                   const u16* __restrict__ xsc,
                                                   const u16* __restrict__ xg,
                                                   u16* __restrict__ ymid) {
    int r = blockIdx.y;
    int d = blockIdx.x * 256 + threadIdx.x;
    __shared__ float hsv[16];
    if (threadIdx.x < 16) hsv[threadIdx.x] = hs[(size_t)r * 16 + threadIdx.x];
    __syncthreads();
    const float* crow = C_mat + (size_t)d * 16;
    float acc = 0.f;
#pragma unroll
    for (int n = 0; n < 16; ++n) acc += hsv[n] * crow[n];
    float xv = u2f(xsc[(size_t)r * 2048 + d]);
    float g = u2f(xg[(size_t)r * 4096 + 2048 + d]);
    float y = acc + D_vec[d] * xv;
    y *= g / (1.f + expf(-g));
    ymid[(size_t)r * 2048 + d] = f2u(y);
}

extern "C" void kernel_launch(void* const* d_in, const int* in_sizes, int n_in,
                              void* d_out, int out_size, void* d_ws, size_t ws_size,
                              hipStream_t stream) {
    (void)in_sizes; (void)n_in;
    const float* x      = (const float*)d_in[0];
    const float* ln_g   = (const float*)d_in[1];
    const float* ln_b   = (const float*)d_in[2];
    const float* W_in   = (const float*)d_in[3];
    const float* conv_w = (const float*)d_in[4];
    const float* conv_b = (const float*)d_in[5];
    const float* A_log  = (const float*)d_in[6];
    const float* B_mat  = (const float*)d_in[7];
    const float* C_mat  = (const float*)d_in[8];
    const float* D_vec  = (const float*)d_in[9];
    const float* Wd     = (const float*)d_in[10];
    const float* bd     = (const float*)d_in[11];
    const float* W_out  = (const float*)d_in[12];
    float* out = (float*)d_out;

    // ---- workspace layout (time-overlaid), ~73 MiB ----
    char* base = (char*)d_ws;
    // bufA 16 MiB: phase 1 = Wt_in (8) + h_ln (8); phase 2 (post GEMM1) = ymid (16)
    u16* Wt_in  = (u16*)base;                          // 4096 x 1024 bf16
    u16* h_ln   = (u16*)base + 4096ull * 1024;         // 4096 x 1024 bf16
    u16* ymid   = (u16*)base;                          // 4096 x 2048 bf16 (reuse)
    // bufB 8 MiB: phase 1 = Wt_d; phase 2 (post GEMM2) = Wt_out (4)
    u16* Wt_d   = (u16*)(base + (16ull << 20));        // 2048 x 2048 bf16
    u16* Wt_out = (u16*)(base + (16ull << 20));        // 1024 x 2048 bf16 (reuse)
    u16* xg     = (u16*)(base + (24ull << 20));        // 4096 x 4096 bf16 (32 MiB)
    u16* xsc    = (u16*)(base + (56ull << 20));        // 4096 x 2048 bf16 (16 MiB)
    float* delta_acc = (float*)(base + (72ull << 20)); // 4096 f32
    float* dAv  = delta_acc + 4096;                    // 4096 x 16 f32
    float* Bxv  = dAv + 4096 * 16;
    float* hsv  = Bxv + 4096 * 16;
    size_t needed = (72ull << 20) + 4096ull * 4 * (1 + 3 * 16);

    if (needed > ws_size) {
        // diagnostic fail: 0x7f7f7f7f f32 = 3.39e38 (finite, unmistakable)
        hipMemsetAsync(d_out, 0x7F, (size_t)out_size * 4, stream);
        return;
    }

    // 1. W_in^T (f32->bf16) ; layernorm
    transpose_f32_bf16<<<dim3(4096 / 32, 1024 / 32), 256, 0, stream>>>(W_in, Wt_in, 1024, 4096);
    ln_kernel<<<4096, 256, 0, stream>>>(x, ln_g, ln_b, h_ln);
    // 2. xg = h @ W_in   (4096x1024)x(1024x4096), bf16 out
    gemm128<0><<<dim3(4096 / 128, 4096 / 128), 256, 0, stream>>>(h_ln, Wt_in, xg, nullptr,
                                                                 4096, 4096, 1024);
    // 3. depthwise conv + silu -> xsc
    conv_silu_kernel<<<dim3(8, 4096), 256, 0, stream>>>(xg, conv_w, conv_b, xsc);
    // 4. Wd^T ; delta_acc = 0 ; fused softplus-rowsum GEMM (no 32MB intermediate)
    transpose_f32_bf16<<<dim3(2048 / 32, 2048 / 32), 256, 0, stream>>>(Wd, Wt_d, 2048, 2048);
    hipMemsetAsync(delta_acc, 0, 4096 * sizeof(float), stream);
    gemm128<1><<<dim3(2048 / 128, 4096 / 128), 256, 0, stream>>>(xsc, Wt_d, delta_acc, bd,
                                                                 4096, 2048, 2048);
    // 5. Bx, dA (delta = delta_acc / 2048 folded in)
    bxda_kernel<<<4096, 256, 0, stream>>>(xsc, B_mat, A_log, delta_acc, dAv, Bxv);
    // 6. selective scan
    scan_kernel<<<32, 64, 0, stream>>>(dAv, Bxv, hsv);
    // 7. ymid = (hs.C + D*xsc) * silu(gate)   (into bufA — Wt_in/h_ln dead)
    ymid_kernel<<<dim3(8, 4096), 256, 0, stream>>>(hsv, C_mat, D_vec, xsc, xg, ymid);
    // 8. W_out^T (into bufB — Wt_d dead) ; out = x + ymid @ W_out (fp32 out)
    transpose_f32_bf16<<<dim3(1024 / 32, 2048 / 32), 256, 0, stream>>>(W_out, Wt_out, 2048, 1024);
    gemm128<2><<<dim3(1024 / 128, 4096 / 128), 256, 0, stream>>>(ymid, Wt_out, out, x,
                                                                 4096, 1024, 2048);
}

// Round 4
// 391.324 us; speedup vs baseline: 1.2296x; 1.2296x over previous
//
#include <hip/hip_runtime.h>
#include <cstdint>
#include <cstddef>

typedef unsigned short u16;
typedef __attribute__((ext_vector_type(4))) float floatx4;
typedef __attribute__((ext_vector_type(8))) __bf16 bf16x8;

// ---------- bf16 helpers ----------
__device__ __forceinline__ float u2f(u16 u) {
    union { unsigned int i; float f; } x;
    x.i = ((unsigned int)u) << 16;
    return x.f;
}
__device__ __forceinline__ u16 f2u(float f) {
    union { float f; unsigned int i; } x;
    x.f = f;
    unsigned int r = x.i + 0x7fffu + ((x.i >> 16) & 1u);   // RNE
    return (u16)(r >> 16);
}

// ---------- transpose tile helper: in (K x N) f32 -> out (N x K) bf16 ----------
__device__ __forceinline__ void tr_tile(const float* __restrict__ in, u16* __restrict__ out,
                                        int K, int N, int bx, int by, float* tile /*32x33*/) {
    int n0 = bx * 32, k0 = by * 32;
    int tx = threadIdx.x & 31, ty = threadIdx.x >> 5;   // ty 0..7
#pragma unroll
    for (int j = 0; j < 4; ++j) {
        int r = ty + j * 8;
        tile[r * 33 + tx] = in[(size_t)(k0 + r) * N + n0 + tx];
    }
    __syncthreads();
#pragma unroll
    for (int j = 0; j < 4; ++j) {
        int r = ty + j * 8;
        out[(size_t)(n0 + r) * K + k0 + tx] = f2u(tile[tx * 33 + r]);
    }
}

// merged W_in (1024x4096) + Wd (2048x2048) transpose: blocks 0..4095 = W_in, 4096..8191 = Wd
__global__ __launch_bounds__(256) void transpose2_kernel(const float* __restrict__ W_in,
                                                         u16* __restrict__ Wt_in,
                                                         const float* __restrict__ Wd,
                                                         u16* __restrict__ Wt_d) {
    __shared__ float tile[32 * 33];
    int blk = blockIdx.x;
    if (blk < 4096) {
        tr_tile(W_in, Wt_in, 1024, 4096, blk & 127, blk >> 7, tile);
    } else {
        int b2 = blk - 4096;
        tr_tile(Wd, Wt_d, 2048, 2048, b2 & 63, b2 >> 6, tile);
    }
}

__global__ __launch_bounds__(256) void transpose1_kernel(const float* __restrict__ in,
                                                         u16* __restrict__ out, int K, int N) {
    __shared__ float tile[32 * 33];
    tr_tile(in, out, K, N, blockIdx.x, blockIdx.y, tile);
}

// ---------- layernorm over D=1024 (f32 in), rows = 4096, bf16 out ----------
__global__ __launch_bounds__(256) void ln_kernel(const float* __restrict__ x,
                                                 const float* __restrict__ gamma,
                                                 const float* __restrict__ beta,
                                                 u16* __restrict__ h) {
    int r = blockIdx.x, t = threadIdx.x;
    const float4* xr = (const float4*)(x + (size_t)r * 1024);
    float4 xv = xr[t];
    float s = xv.x + xv.y + xv.z + xv.w;
    float ss = xv.x * xv.x + xv.y * xv.y + xv.z * xv.z + xv.w * xv.w;
#pragma unroll
    for (int off = 32; off > 0; off >>= 1) {
        s += __shfl_down(s, off, 64);
        ss += __shfl_down(ss, off, 64);
    }
    __shared__ float rs[4], rss[4];
    __shared__ float mu_s, ri_s;
    int wave = t >> 6, lane = t & 63;
    if (lane == 0) { rs[wave] = s; rss[wave] = ss; }
    __syncthreads();
    if (t == 0) {
        float S = rs[0] + rs[1] + rs[2] + rs[3];
        float SS = rss[0] + rss[1] + rss[2] + rss[3];
        float mu = S * (1.f / 1024.f);
        float var = SS * (1.f / 1024.f) - mu * mu;
        mu_s = mu;
        ri_s = rsqrtf(fmaxf(var, 0.f) + 1e-5f);
    }
    __syncthreads();
    float mu = mu_s, ri = ri_s;
    float4 gv = ((const float4*)gamma)[t];
    float4 bv = ((const float4*)beta)[t];
    ushort4 o;
    o.x = f2u((xv.x - mu) * ri * gv.x + bv.x);
    o.y = f2u((xv.y - mu) * ri * gv.y + bv.y);
    o.z = f2u((xv.z - mu) * ri * gv.z + bv.z);
    o.w = f2u((xv.w - mu) * ri * gv.w + bv.w);
    ((ushort4*)(h + (size_t)r * 1024))[t] = o;
}

// ---------- MFMA GEMM, BK=64, tile 128 x TN ----------
__device__ __forceinline__ void gl_lds16(const u16* g, u16* l) {
    __builtin_amdgcn_global_load_lds(
        (const __attribute__((address_space(1))) void*)g,
        (__attribute__((address_space(3))) void*)l, 16, 0, 0);
}

// EPI: 0 = store bf16
//      1 = delta fusion: atomicAdd per-row sum of softplus(acc + biasf32[col]) into (float*)out
//      3 = fp32 partial store at out + blockIdx.z*M*N (split-K)
template <int TN, int EPI>
__global__ __launch_bounds__(256)
void gemm_k(const u16* __restrict__ A, const u16* __restrict__ Bt,
            void* __restrict__ out, const void* __restrict__ aux,
            int M, int N, int K, int Ksub) {
    constexpr int MI = (TN == 128) ? 4 : 2;
    constexpr int BHALF = (TN == 128) ? 4096 : 2048;   // u16 stride between K-halves in Bs
    __shared__ u16 As[128 * 64];
    __shared__ u16 Bs[TN * 64];
    const int tid = threadIdx.x;
    const int wave = tid >> 6, lane = tid & 63;
    const int row0 = blockIdx.y * 128, col0 = blockIdx.x * TN;
    const int koff = blockIdx.z * Ksub;
    const int l16 = lane & 15, q = lane >> 4;
    const int sRow = lane >> 2, sK = (lane & 3) * 8;

    floatx4 acc[MI][4];
#pragma unroll
    for (int i = 0; i < MI; ++i)
#pragma unroll
        for (int j = 0; j < 4; ++j) acc[i][j] = (floatx4){0.f, 0.f, 0.f, 0.f};

    const u16* gA = A + (size_t)(row0 + wave * 32 + sRow) * K + koff + sK;
    u16* lA = As + wave * 1024;   // base within a K-half
    const u16* gB;
    u16* lB;
    if constexpr (TN == 128) {
        gB = Bt + (size_t)(col0 + wave * 32 + sRow) * K + koff + sK;
        lB = Bs + wave * 1024;
    } else {
        gB = Bt + (size_t)(col0 + wave * 16 + sRow) * K + koff + sK;
        lB = Bs + wave * 512;
    }
    const int rowb = (TN == 128) ? (wave >> 1) * 64 : wave * 32;   // wave row base in tile
    const int colb = (TN == 128) ? (wave & 1) * 64 : 0;            // wave col base in tile

    for (int k0 = 0; k0 < Ksub; k0 += 64) {
#pragma unroll
        for (int h = 0; h < 2; ++h) {
            gl_lds16(gA + h * 32, lA + h * 4096);
            gl_lds16(gA + (size_t)16 * K + h * 32, lA + h * 4096 + 512);
            if constexpr (TN == 128) {
                gl_lds16(gB + h * 32, lB + h * 4096);
                gl_lds16(gB + (size_t)16 * K + h * 32, lB + h * 4096 + 512);
            } else {
                gl_lds16(gB + h * 32, lB + h * 2048);
            }
        }
        gA += 64; gB += 64;
        __syncthreads();   // staging visible

#pragma unroll
        for (int h = 0; h < 2; ++h) {
            bf16x8 af[MI], bfr[4];
#pragma unroll
            for (int mi = 0; mi < MI; ++mi)
                af[mi] = *(const bf16x8*)(As + h * 4096 + (rowb + mi * 16 + l16) * 32 + q * 8);
#pragma unroll
            for (int ni = 0; ni < 4; ++ni)
                bfr[ni] = *(const bf16x8*)(Bs + h * BHALF + (colb + ni * 16 + l16) * 32 + q * 8);
#pragma unroll
            for (int mi = 0; mi < MI; ++mi)
#pragma unroll
                for (int ni = 0; ni < 4; ++ni)
                    acc[mi][ni] = __builtin_amdgcn_mfma_f32_16x16x32_bf16(
                        af[mi], bfr[ni], acc[mi][ni], 0, 0, 0);
        }
        __syncthreads();   // compute done before next overwrite
    }

    // epilogue: D row = q*4 + reg, col = l16 (verified m89/m91 mapping)
    const int mB = row0 + rowb;
    const int nB = col0 + colb + l16;
    if constexpr (EPI == 1) {
        float* dacc = (float*)out;
        const float* bias = (const float*)aux;
#pragma unroll
        for (int mi = 0; mi < MI; ++mi) {
#pragma unroll
            for (int rr = 0; rr < 4; ++rr) {
                float s = 0.f;
#pragma unroll
                for (int ni = 0; ni < 4; ++ni) {
                    float t2 = acc[mi][ni][rr] + bias[nB + ni * 16];
                    s += (t2 > 20.f) ? t2 : log1pf(expf(t2));
                }
#pragma unroll
                for (int off = 1; off < 16; off <<= 1)
                    s += __shfl_xor(s, off, 64);
                if (l16 == 0)
                    atomicAdd(&dacc[mB + mi * 16 + q * 4 + rr], s);
            }
        }
    } else {
        float* P = (float*)out;
        if constexpr (EPI == 3) P += (size_t)blockIdx.z * M * N;
#pragma unroll
        for (int mi = 0; mi < MI; ++mi) {
#pragma unroll
            for (int ni = 0; ni < 4; ++ni) {
                int col = nB + ni * 16;
#pragma unroll
                for (int rr = 0; rr < 4; ++rr) {
                    int row = mB + mi * 16 + q * 4 + rr;
                    size_t idx = (size_t)row * N + col;
                    if constexpr (EPI == 0) ((u16*)out)[idx] = f2u(acc[mi][ni][rr]);
                    else                    P[idx] = acc[mi][ni][rr];
                }
            }
        }
    }
}

// ---------- fused depthwise causal conv(K=4) + SiLU + B-projection dots ----------
// one block per row r; thread t handles d = 8t..8t+7; writes xsc row + Bdot[r][0..15]
__global__ __launch_bounds__(256) void conv_bxda_kernel(const u16* __restrict__ xg,
                                                        const float* __restrict__ conv_w,
                                                        const float* __restrict__ conv_b,
                                                        const float* __restrict__ B_mat,
                                                        u16* __restrict__ xsc,
                                                        float* __restrict__ Bdot) {
    int r = blockIdx.x;                        // 0..4095
    int l = r & 2047, bb = r >> 11;
    int t = threadIdx.x, d8 = t * 8;
    float xs[8];
    {
        float4 b0 = *(const float4*)(conv_b + d8);
        float4 b1 = *(const float4*)(conv_b + d8 + 4);
        xs[0] = b0.x; xs[1] = b0.y; xs[2] = b0.z; xs[3] = b0.w;
        xs[4] = b1.x; xs[5] = b1.y; xs[6] = b1.z; xs[7] = b1.w;
    }
    float w[8][4];
#pragma unroll
    for (int j = 0; j < 8; j += 1) {
        float4 wv = *(const float4*)(conv_w + (size_t)(d8 + j) * 4);
        w[j][0] = wv.x; w[j][1] = wv.y; w[j][2] = wv.z; w[j][3] = wv.w;
    }
#pragma unroll
    for (int k = 0; k < 4; ++k) {
        int ls = l + k - 3;
        if (ls >= 0) {
            const u16* row = xg + (size_t)((bb << 11) + ls) * 4096 + d8;
            ushort4 u0 = *(const ushort4*)row;
            ushort4 u1 = *(const ushort4*)(row + 4);
            xs[0] += w[0][k] * u2f(u0.x); xs[1] += w[1][k] * u2f(u0.y);
            xs[2] += w[2][k] * u2f(u0.z); xs[3] += w[3][k] * u2f(u0.w);
            xs[4] += w[4][k] * u2f(u1.x); xs[5] += w[5][k] * u2f(u1.y);
            xs[6] += w[6][k] * u2f(u1.z); xs[7] += w[7][k] * u2f(u1.w);
        }
    }
    ushort4 o0, o1;
#pragma unroll
    for (int j = 0; j < 8; ++j) {
        xs[j] = xs[j] / (1.f + expf(-xs[j]));
        xs[j] = u2f(f2u(xs[j]));   // round to bf16 so Bdot matches stored xsc
    }
    o0.x = f2u(xs[0]); o0.y = f2u(xs[1]); o0.z = f2u(xs[2]); o0.w = f2u(xs[3]);
    o1.x = f2u(xs[4]); o1.y = f2u(xs[5]); o1.z = f2u(xs[6]); o1.w = f2u(xs[7]);
    *(ushort4*)(xsc + (size_t)r * 2048 + d8) = o0;
    *(ushort4*)(xsc + (size_t)r * 2048 + d8 + 4) = o1;

    __shared__ float red[16 * 257];
#pragma unroll
    for (int n = 0; n < 16; ++n) {
        const float* br = B_mat + (size_t)n * 2048 + d8;
        float4 c0 = *(const float4*)br;
        float4 c1 = *(const float4*)(br + 4);
        float a = xs[0] * c0.x + xs[1] * c0.y + xs[2] * c0.z + xs[3] * c0.w
                + xs[4] * c1.x + xs[5] * c1.y + xs[6] * c1.z + xs[7] * c1.w;
        red[n * 257 + t] = a;
    }
    for (int s = 128; s >= 1; s >>= 1) {
        __syncthreads();
        for (int idx = t; idx < s * 16; idx += 256) {
            int n = idx & 15, rr = idx >> 4;
            red[n * 257 + rr] += red[n * 257 + rr + s];
        }
    }
    __syncthreads();
    if (t < 16) Bdot[(size_t)r * 16 + t] = red[t * 257];
}

// ---------- parallel selective scan (dA/Bx computed inline) ----------
__global__ __launch_bounds__(64) void scan_kernel(const float* __restrict__ delta_acc,
                                                  const float* __restrict__ Bdot,
                                                  const float* __restrict__ A_log,
                                                  float* __restrict__ hs) {
    int chain = blockIdx.x;                 // 0..31
    int b = chain >> 4, n = chain & 15;
    int j = threadIdx.x;                    // 0..63, chunk of 32 l's
    float An = -expf(A_log[n]);
    int rbase = b * 2048 + j * 32;
    float a[32], bb[32];
#pragma unroll
    for (int i = 0; i < 32; ++i) {
        float dl = delta_acc[rbase + i] * (1.f / 2048.f);
        a[i] = expf(dl * An);
        bb[i] = Bdot[(size_t)(rbase + i) * 16 + n] * dl;
    }
    float Aacc = 1.f, Bacc = 0.f;
#pragma unroll
    for (int i = 0; i < 32; ++i) {
        Bacc = a[i] * Bacc + bb[i];
        Aacc = a[i] * Aacc;
    }
#pragma unroll
    for (int d = 1; d < 64; d <<= 1) {
        float Ap = __shfl_up(Aacc, d, 64);
        float Bp = __shfl_up(Bacc, d, 64);
        if (j >= d) {
            Bacc = Aacc * Bp + Bacc;
            Aacc = Aacc * Ap;
        }
    }
    float hstart = __shfl_up(Bacc, 1, 64);
    if (j == 0) hstart = 0.f;
    float h = hstart;
    size_t obase = (size_t)rbase * 16 + n;
#pragma unroll
    for (int i = 0; i < 32; ++i) {
        h = a[i] * h + bb[i];
        hs[obase + (size_t)i * 16] = h;
    }
}

// ---------- ymid = (hs·C_mat[d,:] + D_vec*xsc) * silu(gate), bf16 out ----------
__global__ __launch_bounds__(256) void ymid_kernel(const float* __restrict__ hs,
                                                   const float* __restrict__ C_mat,
                                                   const float* __restrict__ D_vec,
                                                   const u16* __restrict__ xsc,
                                                   const u16* __restrict__ xg,
                                                   u16* __restrict__ ymid) {
    int r = blockIdx.y;
    int d = blockIdx.x * 256 + threadIdx.x;
    __shared__ float hsv[16];
    if (threadIdx.x < 16) hsv[threadIdx.x] = hs[(size_t)r * 16 + threadIdx.x];
    __syncthreads();
    const float* crow = C_mat + (size_t)d * 16;
    float acc = 0.f;
#pragma unroll
    for (int n = 0; n < 16; ++n) acc += hsv[n] * crow[n];
    float xv = u2f(xsc[(size_t)r * 2048 + d]);
    float g = u2f(xg[(size_t)r * 4096 + 2048 + d]);
    float y = acc + D_vec[d] * xv;
    y *= g / (1.f + expf(-g));
    ymid[(size_t)r * 2048 + d] = f2u(y);
}

// ---------- out = x + P0 + P1 (split-K reduce + residual), fp32 ----------
__global__ __launch_bounds__(256) void final_add_kernel(const float* __restrict__ x,
                                                        const float* __restrict__ P,
                                                        float* __restrict__ out) {
    size_t i = (size_t)blockIdx.x * 256 + threadIdx.x;
    float4 a = ((const float4*)x)[i];
    float4 p0 = ((const float4*)P)[i];
    float4 p1 = ((const float4*)(P + 4096ull * 1024))[i];
    float4 o;
    o.x = a.x + p0.x + p1.x; o.y = a.y + p0.y + p1.y;
    o.z = a.z + p0.z + p1.z; o.w = a.w + p0.w + p1.w;
    ((float4*)out)[i] = o;
}

extern "C" void kernel_launch(void* const* d_in, const int* in_sizes, int n_in,
                              void* d_out, int out_size, void* d_ws, size_t ws_size,
                              hipStream_t stream) {
    (void)in_sizes; (void)n_in;
    const float* x      = (const float*)d_in[0];
    const float* ln_g   = (const float*)d_in[1];
    const float* ln_b   = (const float*)d_in[2];
    const float* W_in   = (const float*)d_in[3];
    const float* conv_w = (const float*)d_in[4];
    const float* conv_b = (const float*)d_in[5];
    const float* A_log  = (const float*)d_in[6];
    const float* B_mat  = (const float*)d_in[7];
    const float* C_mat  = (const float*)d_in[8];
    const float* D_vec  = (const float*)d_in[9];
    const float* Wd     = (const float*)d_in[10];
    const float* bd     = (const float*)d_in[11];
    const float* W_out  = (const float*)d_in[12];
    float* out = (float*)d_out;

    // ---- workspace layout (time-overlaid), ~73 MiB ----
    char* base = (char*)d_ws;
    u16* Wt_in  = (u16*)base;                          // 4096x1024 bf16 (8 MiB)
    u16* h_ln   = (u16*)base + 4096ull * 1024;         // 4096x1024 bf16 (8 MiB)
    u16* ymid   = (u16*)base;                          // 4096x2048 bf16 (16 MiB, reuse bufA)
    u16* Wt_d   = (u16*)(base + (16ull << 20));        // 2048x2048 bf16 (8 MiB)
    u16* Wt_out = (u16*)(base + (16ull << 20));        // 1024x2048 bf16 (4 MiB, reuse bufB)
    u16* xg     = (u16*)(base + (24ull << 20));        // 4096x4096 bf16 (32 MiB)
    float* Pbuf = (float*)(base + (24ull << 20));      // 2 x 4096x1024 f32 (32 MiB, reuse xg)
    u16* xsc    = (u16*)(base + (56ull << 20));        // 4096x2048 bf16 (16 MiB)
    float* delta_acc = (float*)(base + (72ull << 20)); // 4096 f32
    float* Bdotv = delta_acc + 4096;                   // 4096x16 f32
    float* hsv   = Bdotv + 4096 * 16;                  // 4096x16 f32
    size_t needed = (72ull << 20) + 4096ull * 4 * (1 + 2 * 16);

    if (needed > ws_size) {
        hipMemsetAsync(d_out, 0x7F, (size_t)out_size * 4, stream);  // finite sentinel 3.39e38
        return;
    }

    // 1. W_in^T + Wd^T (merged) ; layernorm ; zero delta accumulator
    transpose2_kernel<<<8192, 256, 0, stream>>>(W_in, Wt_in, Wd, Wt_d);
    ln_kernel<<<4096, 256, 0, stream>>>(x, ln_g, ln_b, h_ln);
    hipMemsetAsync(delta_acc, 0, 4096 * sizeof(float), stream);
    // 2. xg = h @ W_in   (4096x1024)x(1024x4096), 128x128 tile, grid 1024
    gemm_k<128, 0><<<dim3(32, 32, 1), 256, 0, stream>>>(h_ln, Wt_in, xg, nullptr,
                                                        4096, 4096, 1024, 1024);
    // 3. fused conv+silu+B-dots
    conv_bxda_kernel<<<4096, 256, 0, stream>>>(xg, conv_w, conv_b, B_mat, xsc, Bdotv);
    // 4. delta GEMM (softplus rowsum fused), 128x64 tile, grid 1024
    gemm_k<64, 1><<<dim3(32, 32, 1), 256, 0, stream>>>(xsc, Wt_d, delta_acc, bd,
                                                       4096, 2048, 2048, 2048);
    // 5. W_out^T (bufB, Wt_d dead)
    transpose1_kernel<<<dim3(32, 64), 256, 0, stream>>>(W_out, Wt_out, 2048, 1024);
    // 6. selective scan (dA/Bx inline)
    scan_kernel<<<32, 64, 0, stream>>>(delta_acc, Bdotv, A_log, hsv);
    // 7. ymid (into bufA; h_ln/Wt_in dead)
    ymid_kernel<<<dim3(8, 4096), 256, 0, stream>>>(hsv, C_mat, D_vec, xsc, xg, ymid);
    // 8. out-GEMM split-K=2 into Pbuf (xg region dead after ymid), 128x64 tile, grid 1024
    gemm_k<64, 3><<<dim3(16, 32, 2), 256, 0, stream>>>(ymid, Wt_out, Pbuf, nullptr,
                                                       4096, 1024, 2048, 1024);
    // 9. out = x + P0 + P1
    final_add_kernel<<<4096, 256, 0, stream>>>(x, Pbuf, out);
}